// Round 16
// baseline (158.083 us; speedup 1.0000x reference)
//
#include <hip/hip_runtime.h>
#include <math.h>

constexpr int BLK = 256;
constexpr int NB_MAX = 256;      // max coarse buckets (supports N <= 131072)
constexpr int BSHIFT = 9;        // 512 nodes per bucket
constexpr int BSPAN = 1 << BSHIFT;
constexpr int CAP = 10240;       // per-bucket bin capacity (mean 8192 @ E=1.6M, +22 sigma)
constexpr int CAP2 = 12800;      // per-bucket padded col capacity (mean 9984, +31 sigma)
constexpr int EPT2 = 16;         // edges per thread in binpass
constexpr int EPBB = BLK * EPT2; // 4096 edges per block

typedef unsigned short u16;
typedef __attribute__((ext_vector_type(8))) short short8_t;
typedef __attribute__((ext_vector_type(4))) float f32x4;

// ---- bf16 helpers ----
__device__ __forceinline__ u16 f2bf(float f) {
  union { float f; unsigned int i; } v;
  v.f = f;
  unsigned int r = v.i + 0x7FFF + ((v.i >> 16) & 1);  // RNE
  return (u16)(r >> 16);
}
__device__ __forceinline__ float bf_lo(unsigned u) {
  union { unsigned int i; float f; } v;
  v.i = u << 16;
  return v.f;
}
__device__ __forceinline__ float bf_hi(unsigned u) {
  union { unsigned int i; float f; } v;
  v.i = u & 0xFFFF0000u;
  return v.f;
}

// ---------------- pass 1: coarse binning into block-private chunks ----------------
__global__ void __launch_bounds__(BLK) binpass(const int* __restrict__ src,
                                               const int* __restrict__ dst,
                                               int e, int* __restrict__ bins,
                                               int* __restrict__ tail) {
  __shared__ int lcnt[NB_MAX], gbase[NB_MAX], lcur[NB_MAX];
  const int tid = threadIdx.x;
  lcnt[tid] = 0;
  lcur[tid] = 0;
  __syncthreads();
  const int i0 = blockIdx.x * EPBB;
  int bb[EPT2], pk[EPT2];
#pragma unroll
  for (int k = 0; k < EPT2; k++) {
    int i = i0 + k * BLK + tid;
    if (i < e) {
      int d = dst[i], s = src[i];
      bb[k] = d >> BSHIFT;
      pk[k] = ((d & (BSPAN - 1)) << 23) | s;   // src < 2^23, dlo < 2^9
      atomicAdd(&lcnt[bb[k]], 1);
    } else {
      bb[k] = -1;
    }
  }
  __syncthreads();
  gbase[tid] = atomicAdd(&tail[tid], lcnt[tid]);  // reserve contiguous chunk per bucket
  __syncthreads();
#pragma unroll
  for (int k = 0; k < EPT2; k++) {
    if (bb[k] >= 0) {
      int idx = atomicAdd(&lcur[bb[k]], 1);
      bins[bb[k] * CAP + gbase[bb[k]] + idx] = pk[k];
    }
  }
}

// ---------------- pass 2: per-bucket counting sort into FIXED col region ----------------
// Bucket b owns col[b*CAP2 .. b*CAP2+CAP2). Per-node segments padded to mult-of-8
// with pad entries = n (zero row). wdesc[node] = (beg<<10) | ceil(deg/8).
__global__ void __launch_bounds__(BLK) bucket_sort(const int* __restrict__ bins,
                                                   const int* __restrict__ tail,
                                                   unsigned* __restrict__ wdesc,
                                                   int* __restrict__ col,
                                                   float* __restrict__ dinv, int n) {
  __shared__ int hist[BSPAN], lpre[BSPAN], lcur[BSPAN], sd[BLK];
  const int b = blockIdx.x, tid = threadIdx.x;
  const int cnt = tail[b];
  const int base = b * CAP2;
  const int node0 = b << BSHIFT;
  const int nNodes = min(BSPAN, n - node0);
  const int* bin = bins + (size_t)b * CAP;

  hist[tid] = 0; hist[tid + BLK] = 0;
  lcur[tid] = 0; lcur[tid + BLK] = 0;
  __syncthreads();
  for (int j = tid; j < cnt; j += BLK) atomicAdd(&hist[(unsigned)bin[j] >> 23], 1);
  __syncthreads();
  // exclusive scan over PADDED counts (2 per thread)
  int h0 = hist[2 * tid], h1 = hist[2 * tid + 1];
  int p0 = (h0 + 7) & ~7, p1 = (h1 + 7) & ~7;
  int ts = p0 + p1;
  sd[tid] = ts;
  __syncthreads();
  for (int off = 1; off < BLK; off <<= 1) {
    int t = (tid >= off) ? sd[tid - off] : 0;
    __syncthreads();
    sd[tid] += t;
    __syncthreads();
  }
  int ex = sd[tid] - ts;
  lpre[2 * tid] = ex;
  lpre[2 * tid + 1] = ex + p0;
  __syncthreads();
  for (int d = tid; d < nNodes; d += BLK) {
    int hd = hist[d];
    int begd = base + lpre[d];
    wdesc[node0 + d] = ((unsigned)begd << 10) | (unsigned)((hd + 7) >> 3);
    dinv[node0 + d] = rsqrtf((float)hd + 1.0f);
    int pe = (hd + 7) & ~7;
    for (int t = hd; t < pe; t++) col[begd + t] = n;  // pad -> zero row
  }
  __syncthreads();
  for (int j = tid; j < cnt; j += BLK) {
    int pkv = bin[j];
    int dlo = (unsigned)pkv >> 23;
    int idx = atomicAdd(&lcur[dlo], 1);
    col[base + lpre[dlo] + idx] = pkv & 0x7FFFFF;
  }
}

// ---------------- MFMA GEMM via split-bf16: G = bf16((X @ W) * dinv) ----------------
// 3 MFMA per tile (hi*hi + lo*hi + hi*lo); fp32-grade accuracy. Block 0 also
// zeroes the pad row(s). BLK16: output channel-blocked as G[ct][(n+1)][16]
// (each 16-col tile its own 3.2MB table -> fits per-XCD L2 for the gather).
template <int K, int M, bool BLK16>
__global__ void __launch_bounds__(BLK) gemm_mfma(const float* __restrict__ X,
                                                 const float* __restrict__ W,
                                                 const float* __restrict__ dinv,
                                                 u16* __restrict__ G, int n) {
  constexpr int KC = K / 32;   // K-chunks
  constexpr int CT = M / 16;   // 16-col tiles
  constexpr int PADK = K + 8;  // row stride 272B (K=128): 2-way bank alias = free
  __shared__ u16 wt_hi[M][PADK];
  __shared__ u16 wt_lo[M][PADK];
  const int tid = threadIdx.x;
  const int lane = tid & 63;
  const int wv = tid >> 6;

  if (blockIdx.x == 0 && tid < M) {  // zero pad row(s)
    if constexpr (BLK16)
      G[((size_t)(tid >> 4) * (n + 1) + n) * 16 + (tid & 15)] = 0;
    else
      G[(size_t)n * M + tid] = 0;
  }

  // stage W transposed + hi/lo split (one-time; reads coalesced)
  for (int i = tid; i < K * M; i += BLK) {
    int k = i / M, m = i % M;
    float w = W[i];
    unsigned wb = __float_as_uint(w);
    wt_hi[m][k] = (u16)(wb >> 16);                       // truncation hi
    wt_lo[m][k] = f2bf(w - __uint_as_float(wb & 0xFFFF0000u));
  }
  __syncthreads();

  const int r16 = lane & 15;
  const int oct = lane >> 4;
  int rowA = blockIdx.x * 64 + wv * 16 + r16;
  if (rowA >= n) rowA = n - 1;  // clamp (stores guarded)

  f32x4 acc[CT];
#pragma unroll
  for (int ct = 0; ct < CT; ct++) acc[ct] = (f32x4){0.f, 0.f, 0.f, 0.f};

#pragma unroll
  for (int kc = 0; kc < KC; kc++) {
    const float* xp = &X[(size_t)rowA * K + kc * 32 + oct * 8];
    float4 v0 = *(const float4*)xp;
    float4 v1 = *(const float4*)(xp + 4);
    float vv[8] = {v0.x, v0.y, v0.z, v0.w, v1.x, v1.y, v1.z, v1.w};
    short8_t ahi, alo;
#pragma unroll
    for (int j = 0; j < 8; j++) {
      unsigned xb = __float_as_uint(vv[j]);
      ahi[j] = (short)(xb >> 16);  // truncation hi
      alo[j] = (short)f2bf(vv[j] - __uint_as_float(xb & 0xFFFF0000u));
    }
#pragma unroll
    for (int ct = 0; ct < CT; ct++) {
      short8_t bhi = *(const short8_t*)&wt_hi[ct * 16 + r16][kc * 32 + oct * 8];
      short8_t blo = *(const short8_t*)&wt_lo[ct * 16 + r16][kc * 32 + oct * 8];
      acc[ct] = __builtin_amdgcn_mfma_f32_16x16x32_bf16(ahi, bhi, acc[ct], 0, 0, 0);
      acc[ct] = __builtin_amdgcn_mfma_f32_16x16x32_bf16(alo, bhi, acc[ct], 0, 0, 0);
      acc[ct] = __builtin_amdgcn_mfma_f32_16x16x32_bf16(ahi, blo, acc[ct], 0, 0, 0);
    }
  }

  // epilogue: C row = oct*4 + reg, col = ct*16 + r16
  const int rbase = blockIdx.x * 64 + wv * 16 + oct * 4;
  float dv[4];
#pragma unroll
  for (int r = 0; r < 4; r++) {
    int gr = rbase + r;
    dv[r] = (gr < n) ? dinv[gr] : 0.f;
  }
#pragma unroll
  for (int ct = 0; ct < CT; ct++) {
#pragma unroll
    for (int r = 0; r < 4; r++) {
      int gr = rbase + r;
      if (gr < n) {
        u16 val = f2bf(acc[ct][r] * dv[r]);
        if constexpr (BLK16)
          G[((size_t)ct * (n + 1) + gr) * 16 + r16] = val;
        else
          G[(size_t)gr * M + ct * 16 + r16] = val;
      }
    }
  }
}

// ---------------- agg1: channel-blocked, grid.y = 4 passes ----------------
// Pass p gathers from its own 3.2MB table gball[p] (L2-resident). 4 lanes per
// node, 4 ch per lane; per iter 2 broadcast int4 col loads + 8 uint2 gathers.
__global__ void __launch_bounds__(BLK) agg1_blk(const u16* __restrict__ gball,
                                                const unsigned* __restrict__ wdesc,
                                                const int* __restrict__ col,
                                                const float* __restrict__ dinv,
                                                const float* __restrict__ b1,
                                                float* __restrict__ h, int n) {
  const int tid = threadIdx.x;
  const int pass = blockIdx.y;
  const u16* gb = gball + (size_t)pass * (n + 1) * 16;
  const int node = blockIdx.x * 64 + (tid >> 2);
  if (node >= n) return;
  const int cl = tid & 3;
  unsigned w = wdesc[node];
  int beg = (int)(w >> 10), nb = (int)(w & 1023);
  float a0, a1, a2, a3;
  {  // self-loop slice
    uint2 u = *(const uint2*)&gb[(size_t)node * 16 + cl * 4];
    a0 = bf_lo(u.x); a1 = bf_hi(u.x); a2 = bf_lo(u.y); a3 = bf_hi(u.y);
  }
  for (int i = 0; i < nb; i++) {
    int j = beg + i * 8;
    int4 sA = *(const int4*)&col[j];
    int4 sB = *(const int4*)&col[j + 4];
    uint2 u0 = *(const uint2*)&gb[(size_t)sA.x * 16 + cl * 4];
    uint2 u1 = *(const uint2*)&gb[(size_t)sA.y * 16 + cl * 4];
    uint2 u2 = *(const uint2*)&gb[(size_t)sA.z * 16 + cl * 4];
    uint2 u3 = *(const uint2*)&gb[(size_t)sA.w * 16 + cl * 4];
    uint2 u4 = *(const uint2*)&gb[(size_t)sB.x * 16 + cl * 4];
    uint2 u5 = *(const uint2*)&gb[(size_t)sB.y * 16 + cl * 4];
    uint2 u6 = *(const uint2*)&gb[(size_t)sB.z * 16 + cl * 4];
    uint2 u7 = *(const uint2*)&gb[(size_t)sB.w * 16 + cl * 4];
    a0 += bf_lo(u0.x); a1 += bf_hi(u0.x); a2 += bf_lo(u0.y); a3 += bf_hi(u0.y);
    a0 += bf_lo(u1.x); a1 += bf_hi(u1.x); a2 += bf_lo(u1.y); a3 += bf_hi(u1.y);
    a0 += bf_lo(u2.x); a1 += bf_hi(u2.x); a2 += bf_lo(u2.y); a3 += bf_hi(u2.y);
    a0 += bf_lo(u3.x); a1 += bf_hi(u3.x); a2 += bf_lo(u3.y); a3 += bf_hi(u3.y);
    a0 += bf_lo(u4.x); a1 += bf_hi(u4.x); a2 += bf_lo(u4.y); a3 += bf_hi(u4.y);
    a0 += bf_lo(u5.x); a1 += bf_hi(u5.x); a2 += bf_lo(u5.y); a3 += bf_hi(u5.y);
    a0 += bf_lo(u6.x); a1 += bf_hi(u6.x); a2 += bf_lo(u6.y); a3 += bf_hi(u6.y);
    a0 += bf_lo(u7.x); a1 += bf_hi(u7.x); a2 += bf_lo(u7.y); a3 += bf_hi(u7.y);
  }
  float di = dinv[node];
  float4 bv = *(const float4*)&b1[pass * 16 + cl * 4];
  float4 o;
  o.x = a0 * di + bv.x; o.y = a1 * di + bv.y;
  o.z = a2 * di + bv.z; o.w = a3 * di + bv.w;
  o.x = o.x > 0.f ? o.x : 0.f;
  o.y = o.y > 0.f ? o.y : 0.f;
  o.z = o.z > 0.f ? o.z : 0.f;
  o.w = o.w > 0.f ? o.w : 0.f;
  *(float4*)&h[(size_t)node * 64 + pass * 16 + cl * 4] = o;
}

// ---------------- aggregation layer 2 (one node per 8-lane group) ----------------
__global__ void __launch_bounds__(BLK) agg2_kernel(const u16* __restrict__ gs,
                                                   const unsigned* __restrict__ wdesc,
                                                   const int* __restrict__ col,
                                                   const float* __restrict__ dinv,
                                                   const float* __restrict__ bias,
                                                   float* __restrict__ out, int n) {
  const int tid = threadIdx.x;
  const int node = blockIdx.x * 32 + (tid >> 3);
  if (node >= n) return;
  const int cs = tid & 7;
  unsigned w = wdesc[node];
  int beg = (int)(w >> 10), nb = (int)(w & 1023);
  float a0, a1, a2, a3;
  {
    uint2 u = *(const uint2*)&gs[(size_t)node * 32 + cs * 4];
    a0 = bf_lo(u.x); a1 = bf_hi(u.x); a2 = bf_lo(u.y); a3 = bf_hi(u.y);
  }
  for (int i = 0; i < nb; i++) {
    int j = beg + i * 8;
    int4 sA = *(const int4*)&col[j];
    int4 sB = *(const int4*)&col[j + 4];
    uint2 u0 = *(const uint2*)&gs[(size_t)sA.x * 32 + cs * 4];
    uint2 u1 = *(const uint2*)&gs[(size_t)sA.y * 32 + cs * 4];
    uint2 u2 = *(const uint2*)&gs[(size_t)sA.z * 32 + cs * 4];
    uint2 u3 = *(const uint2*)&gs[(size_t)sA.w * 32 + cs * 4];
    uint2 u4 = *(const uint2*)&gs[(size_t)sB.x * 32 + cs * 4];
    uint2 u5 = *(const uint2*)&gs[(size_t)sB.y * 32 + cs * 4];
    uint2 u6 = *(const uint2*)&gs[(size_t)sB.z * 32 + cs * 4];
    uint2 u7 = *(const uint2*)&gs[(size_t)sB.w * 32 + cs * 4];
    a0 += bf_lo(u0.x); a1 += bf_hi(u0.x); a2 += bf_lo(u0.y); a3 += bf_hi(u0.y);
    a0 += bf_lo(u1.x); a1 += bf_hi(u1.x); a2 += bf_lo(u1.y); a3 += bf_hi(u1.y);
    a0 += bf_lo(u2.x); a1 += bf_hi(u2.x); a2 += bf_lo(u2.y); a3 += bf_hi(u2.y);
    a0 += bf_lo(u3.x); a1 += bf_hi(u3.x); a2 += bf_lo(u3.y); a3 += bf_hi(u3.y);
    a0 += bf_lo(u4.x); a1 += bf_hi(u4.x); a2 += bf_lo(u4.y); a3 += bf_hi(u4.y);
    a0 += bf_lo(u5.x); a1 += bf_hi(u5.x); a2 += bf_lo(u5.y); a3 += bf_hi(u5.y);
    a0 += bf_lo(u6.x); a1 += bf_hi(u6.x); a2 += bf_lo(u6.y); a3 += bf_hi(u6.y);
    a0 += bf_lo(u7.x); a1 += bf_hi(u7.x); a2 += bf_lo(u7.y); a3 += bf_hi(u7.y);
  }
  float di = dinv[node];
  float4 bv = *(const float4*)&bias[cs * 4];
  float4 o;
  o.x = a0 * di + bv.x; o.y = a1 * di + bv.y;
  o.z = a2 * di + bv.z; o.w = a3 * di + bv.w;
  o.x = o.x > 0.f ? o.x : 0.f;
  o.y = o.y > 0.f ? o.y : 0.f;
  o.z = o.z > 0.f ? o.z : 0.f;
  o.w = o.w > 0.f ? o.w : 0.f;
  *(float4*)&out[(size_t)node * 32 + cs * 4] = o;
}

// ---------------- launcher ----------------

extern "C" void kernel_launch(void* const* d_in, const int* in_sizes, int n_in,
                              void* d_out, int out_size, void* d_ws, size_t ws_size,
                              hipStream_t stream) {
  const float* x = (const float*)d_in[0];
  const int* ei = (const int*)d_in[1];
  const float* W1 = (const float*)d_in[2];
  const float* b1 = (const float*)d_in[3];
  const float* W2 = (const float*)d_in[4];
  const float* b2 = (const float*)d_in[5];

  const int N = in_sizes[0] / 128;
  const int E = in_sizes[1] / 2;
  const int* src = ei;
  const int* dst = ei + E;
  const int nb = (N + BSPAN - 1) >> BSHIFT;  // # coarse buckets (196 @ N=100K)

  char* p = (char*)d_ws;
  auto take = [&](size_t bytes) -> char* {
    char* q = p;
    p += (bytes + 255) & ~(size_t)255;
    return q;
  };
  int* bins = (int*)take((size_t)NB_MAX * CAP * 4);
  int* tail = (int*)take(NB_MAX * 4);
  unsigned* wdesc = (unsigned*)take((size_t)N * 4);
  int* col = (int*)take((size_t)nb * CAP2 * 4);
  float* dinv = (float*)take((size_t)N * 4);
  u16* g1b = (u16*)take((size_t)4 * (N + 1) * 16 * 2);  // 4 channel-blocked tables
  float* h = (float*)take((size_t)N * 64 * 4);
  u16* g2 = (u16*)take((size_t)(N + 1) * 32 * 2);       // +1 zero row

  hipMemsetAsync(tail, 0, NB_MAX * 4, stream);

  binpass<<<(E + EPBB - 1) / EPBB, BLK, 0, stream>>>(src, dst, E, bins, tail);
  bucket_sort<<<nb, BLK, 0, stream>>>(bins, tail, wdesc, col, dinv, N);

  gemm_mfma<128, 64, true><<<(N + 63) / 64, BLK, 0, stream>>>(x, W1, dinv, g1b, N);
  agg1_blk<<<dim3((N + 63) / 64, 4), BLK, 0, stream>>>(g1b, wdesc, col, dinv, b1, h, N);
  gemm_mfma<64, 32, false><<<(N + 63) / 64, BLK, 0, stream>>>(h, W2, dinv, g2, N);
  agg2_kernel<<<(N + 31) / 32, BLK, 0, stream>>>(g2, wdesc, col, dinv, b2, (float*)d_out, N);
}

// Round 17
// 138.020 us; speedup vs baseline: 1.1454x; 1.1454x over previous
//
#include <hip/hip_runtime.h>
#include <math.h>

constexpr int BLK = 256;
constexpr int NB_MAX = 256;      // max coarse buckets (supports N <= 131072)
constexpr int BSHIFT = 9;        // 512 nodes per bucket
constexpr int BSPAN = 1 << BSHIFT;
constexpr int CAP = 10240;       // per-bucket bin capacity (mean 8192 @ E=1.6M, +22 sigma)
constexpr int CAP2 = 12800;      // per-bucket padded col capacity (mean 9984, +31 sigma)
constexpr int EPT2 = 16;         // edges per thread in binpass
constexpr int EPBB = BLK * EPT2; // 4096 edges per block

typedef unsigned short u16;
typedef __attribute__((ext_vector_type(8))) short short8_t;
typedef __attribute__((ext_vector_type(4))) float f32x4;

// ---- bf16 helpers ----
__device__ __forceinline__ u16 f2bf(float f) {
  union { float f; unsigned int i; } v;
  v.f = f;
  unsigned int r = v.i + 0x7FFF + ((v.i >> 16) & 1);  // RNE
  return (u16)(r >> 16);
}
__device__ __forceinline__ float bf_lo(unsigned u) {
  union { unsigned int i; float f; } v;
  v.i = u << 16;
  return v.f;
}
__device__ __forceinline__ float bf_hi(unsigned u) {
  union { unsigned int i; float f; } v;
  v.i = u & 0xFFFF0000u;
  return v.f;
}

// ---------------- pass 1: coarse binning into block-private chunks ----------------
__global__ void __launch_bounds__(BLK) binpass(const int* __restrict__ src,
                                               const int* __restrict__ dst,
                                               int e, int* __restrict__ bins,
                                               int* __restrict__ tail) {
  __shared__ int lcnt[NB_MAX], gbase[NB_MAX], lcur[NB_MAX];
  const int tid = threadIdx.x;
  lcnt[tid] = 0;
  lcur[tid] = 0;
  __syncthreads();
  const int i0 = blockIdx.x * EPBB;
  int bb[EPT2], pk[EPT2];
#pragma unroll
  for (int k = 0; k < EPT2; k++) {
    int i = i0 + k * BLK + tid;
    if (i < e) {
      int d = dst[i], s = src[i];
      bb[k] = d >> BSHIFT;
      pk[k] = ((d & (BSPAN - 1)) << 23) | s;   // src < 2^23, dlo < 2^9
      atomicAdd(&lcnt[bb[k]], 1);
    } else {
      bb[k] = -1;
    }
  }
  __syncthreads();
  gbase[tid] = atomicAdd(&tail[tid], lcnt[tid]);  // reserve contiguous chunk per bucket
  __syncthreads();
#pragma unroll
  for (int k = 0; k < EPT2; k++) {
    if (bb[k] >= 0) {
      int idx = atomicAdd(&lcur[bb[k]], 1);
      bins[bb[k] * CAP + gbase[bb[k]] + idx] = pk[k];
    }
  }
}

// ---------------- pass 2: per-bucket counting sort into FIXED col region ----------------
// Bucket b owns col[b*CAP2 .. b*CAP2+CAP2). Per-node segments padded to mult-of-8
// with pad entries = n (zero row). wdesc[node] = (beg<<10) | ceil(deg/8).
__global__ void __launch_bounds__(BLK) bucket_sort(const int* __restrict__ bins,
                                                   const int* __restrict__ tail,
                                                   unsigned* __restrict__ wdesc,
                                                   int* __restrict__ col,
                                                   float* __restrict__ dinv, int n) {
  __shared__ int hist[BSPAN], lpre[BSPAN], lcur[BSPAN], sd[BLK];
  const int b = blockIdx.x, tid = threadIdx.x;
  const int cnt = tail[b];
  const int base = b * CAP2;
  const int node0 = b << BSHIFT;
  const int nNodes = min(BSPAN, n - node0);
  const int* bin = bins + (size_t)b * CAP;

  hist[tid] = 0; hist[tid + BLK] = 0;
  lcur[tid] = 0; lcur[tid + BLK] = 0;
  __syncthreads();
  for (int j = tid; j < cnt; j += BLK) atomicAdd(&hist[(unsigned)bin[j] >> 23], 1);
  __syncthreads();
  // exclusive scan over PADDED counts (2 per thread)
  int h0 = hist[2 * tid], h1 = hist[2 * tid + 1];
  int p0 = (h0 + 7) & ~7, p1 = (h1 + 7) & ~7;
  int ts = p0 + p1;
  sd[tid] = ts;
  __syncthreads();
  for (int off = 1; off < BLK; off <<= 1) {
    int t = (tid >= off) ? sd[tid - off] : 0;
    __syncthreads();
    sd[tid] += t;
    __syncthreads();
  }
  int ex = sd[tid] - ts;
  lpre[2 * tid] = ex;
  lpre[2 * tid + 1] = ex + p0;
  __syncthreads();
  for (int d = tid; d < nNodes; d += BLK) {
    int hd = hist[d];
    int begd = base + lpre[d];
    wdesc[node0 + d] = ((unsigned)begd << 10) | (unsigned)((hd + 7) >> 3);
    dinv[node0 + d] = rsqrtf((float)hd + 1.0f);
    int pe = (hd + 7) & ~7;
    for (int t = hd; t < pe; t++) col[begd + t] = n;  // pad -> zero row
  }
  __syncthreads();
  for (int j = tid; j < cnt; j += BLK) {
    int pkv = bin[j];
    int dlo = (unsigned)pkv >> 23;
    int idx = atomicAdd(&lcur[dlo], 1);
    col[base + lpre[dlo] + idx] = pkv & 0x7FFFFF;
  }
}

// ---------------- MFMA GEMM via split-bf16: G = bf16((X @ W) * dinv) ----------------
// 3 MFMA per tile (hi*hi + lo*hi + hi*lo); fp32-grade accuracy. RT row-tiles of
// 64 rows per block amortize the one-time W staging. Block 0 zeroes pad row.
template <int K, int M, int RT>
__global__ void __launch_bounds__(BLK) gemm_mfma(const float* __restrict__ X,
                                                 const float* __restrict__ W,
                                                 const float* __restrict__ dinv,
                                                 u16* __restrict__ G, int n) {
  constexpr int KC = K / 32;   // K-chunks
  constexpr int CT = M / 16;   // 16-col tiles
  constexpr int PADK = K + 8;  // row stride 272B (K=128): 2-way bank alias = free
  __shared__ u16 wt_hi[M][PADK];
  __shared__ u16 wt_lo[M][PADK];
  const int tid = threadIdx.x;
  const int lane = tid & 63;
  const int wv = tid >> 6;

  if (blockIdx.x == 0 && tid < M) G[(size_t)n * M + tid] = 0;  // zero pad row

  // stage W transposed + hi/lo split (one-time; reads coalesced)
  for (int i = tid; i < K * M; i += BLK) {
    int k = i / M, m = i % M;
    float w = W[i];
    unsigned wb = __float_as_uint(w);
    wt_hi[m][k] = (u16)(wb >> 16);                       // truncation hi
    wt_lo[m][k] = f2bf(w - __uint_as_float(wb & 0xFFFF0000u));
  }
  __syncthreads();

  const int r16 = lane & 15;
  const int oct = lane >> 4;

#pragma unroll
  for (int rt = 0; rt < RT; rt++) {
    int rowA = blockIdx.x * (64 * RT) + rt * 64 + wv * 16 + r16;
    if (rowA >= n) rowA = n - 1;  // clamp (stores guarded)

    f32x4 acc[CT];
#pragma unroll
    for (int ct = 0; ct < CT; ct++) acc[ct] = (f32x4){0.f, 0.f, 0.f, 0.f};

#pragma unroll
    for (int kc = 0; kc < KC; kc++) {
      const float* xp = &X[(size_t)rowA * K + kc * 32 + oct * 8];
      float4 v0 = *(const float4*)xp;
      float4 v1 = *(const float4*)(xp + 4);
      float vv[8] = {v0.x, v0.y, v0.z, v0.w, v1.x, v1.y, v1.z, v1.w};
      short8_t ahi, alo;
#pragma unroll
      for (int j = 0; j < 8; j++) {
        unsigned xb = __float_as_uint(vv[j]);
        ahi[j] = (short)(xb >> 16);  // truncation hi
        alo[j] = (short)f2bf(vv[j] - __uint_as_float(xb & 0xFFFF0000u));
      }
#pragma unroll
      for (int ct = 0; ct < CT; ct++) {
        short8_t bhi = *(const short8_t*)&wt_hi[ct * 16 + r16][kc * 32 + oct * 8];
        short8_t blo = *(const short8_t*)&wt_lo[ct * 16 + r16][kc * 32 + oct * 8];
        acc[ct] = __builtin_amdgcn_mfma_f32_16x16x32_bf16(ahi, bhi, acc[ct], 0, 0, 0);
        acc[ct] = __builtin_amdgcn_mfma_f32_16x16x32_bf16(alo, bhi, acc[ct], 0, 0, 0);
        acc[ct] = __builtin_amdgcn_mfma_f32_16x16x32_bf16(ahi, blo, acc[ct], 0, 0, 0);
      }
    }

    // epilogue: C row = oct*4 + reg, col = ct*16 + r16
    const int rbase = blockIdx.x * (64 * RT) + rt * 64 + wv * 16 + oct * 4;
    float dv[4];
#pragma unroll
    for (int r = 0; r < 4; r++) {
      int gr = rbase + r;
      dv[r] = (gr < n) ? dinv[gr] : 0.f;
    }
#pragma unroll
    for (int ct = 0; ct < CT; ct++) {
#pragma unroll
      for (int r = 0; r < 4; r++) {
        int gr = rbase + r;
        if (gr < n) G[(size_t)gr * M + ct * 16 + r16] = f2bf(acc[ct][r] * dv[r]);
      }
    }
  }
}

// ---------------- aggregation (one node per lane-group, no shuffles) ----------------
// gs (bf16, N+1 rows; row n zero). Segments padded to mult-of-8 with col=n.

// layer 1: 16 lanes per node (cs = 4-channel slice). Per iter: 2 broadcast int4
// col loads + 8 row gathers (128B line each) + 32 unpack-adds per lane.
__global__ void __launch_bounds__(BLK) agg1_kernel(const u16* __restrict__ gs,
                                                   const unsigned* __restrict__ wdesc,
                                                   const int* __restrict__ col,
                                                   const float* __restrict__ dinv,
                                                   const float* __restrict__ bias,
                                                   float* __restrict__ out, int n) {
  const int tid = threadIdx.x;
  const int node = blockIdx.x * 16 + (tid >> 4);
  if (node >= n) return;
  const int cs = tid & 15;
  unsigned w = wdesc[node];
  int beg = (int)(w >> 10), nb = (int)(w & 1023);
  float a0, a1, a2, a3;
  {  // self-loop slice (unconditional: this group owns the node)
    uint2 u = *(const uint2*)&gs[(size_t)node * 64 + cs * 4];
    a0 = bf_lo(u.x); a1 = bf_hi(u.x); a2 = bf_lo(u.y); a3 = bf_hi(u.y);
  }
  for (int i = 0; i < nb; i++) {
    int j = beg + i * 8;
    int4 sA = *(const int4*)&col[j];
    int4 sB = *(const int4*)&col[j + 4];
    uint2 u0 = *(const uint2*)&gs[(size_t)sA.x * 64 + cs * 4];
    uint2 u1 = *(const uint2*)&gs[(size_t)sA.y * 64 + cs * 4];
    uint2 u2 = *(const uint2*)&gs[(size_t)sA.z * 64 + cs * 4];
    uint2 u3 = *(const uint2*)&gs[(size_t)sA.w * 64 + cs * 4];
    uint2 u4 = *(const uint2*)&gs[(size_t)sB.x * 64 + cs * 4];
    uint2 u5 = *(const uint2*)&gs[(size_t)sB.y * 64 + cs * 4];
    uint2 u6 = *(const uint2*)&gs[(size_t)sB.z * 64 + cs * 4];
    uint2 u7 = *(const uint2*)&gs[(size_t)sB.w * 64 + cs * 4];
    a0 += bf_lo(u0.x); a1 += bf_hi(u0.x); a2 += bf_lo(u0.y); a3 += bf_hi(u0.y);
    a0 += bf_lo(u1.x); a1 += bf_hi(u1.x); a2 += bf_lo(u1.y); a3 += bf_hi(u1.y);
    a0 += bf_lo(u2.x); a1 += bf_hi(u2.x); a2 += bf_lo(u2.y); a3 += bf_hi(u2.y);
    a0 += bf_lo(u3.x); a1 += bf_hi(u3.x); a2 += bf_lo(u3.y); a3 += bf_hi(u3.y);
    a0 += bf_lo(u4.x); a1 += bf_hi(u4.x); a2 += bf_lo(u4.y); a3 += bf_hi(u4.y);
    a0 += bf_lo(u5.x); a1 += bf_hi(u5.x); a2 += bf_lo(u5.y); a3 += bf_hi(u5.y);
    a0 += bf_lo(u6.x); a1 += bf_hi(u6.x); a2 += bf_lo(u6.y); a3 += bf_hi(u6.y);
    a0 += bf_lo(u7.x); a1 += bf_hi(u7.x); a2 += bf_lo(u7.y); a3 += bf_hi(u7.y);
  }
  float di = dinv[node];
  float4 bv = *(const float4*)&bias[cs * 4];
  float4 o;
  o.x = a0 * di + bv.x; o.y = a1 * di + bv.y;
  o.z = a2 * di + bv.z; o.w = a3 * di + bv.w;
  o.x = o.x > 0.f ? o.x : 0.f;
  o.y = o.y > 0.f ? o.y : 0.f;
  o.z = o.z > 0.f ? o.z : 0.f;
  o.w = o.w > 0.f ? o.w : 0.f;
  *(float4*)&out[(size_t)node * 64 + cs * 4] = o;
}

// layer 2: 8 lanes per node (cs = 4-channel slice of 32). Same batch structure.
__global__ void __launch_bounds__(BLK) agg2_kernel(const u16* __restrict__ gs,
                                                   const unsigned* __restrict__ wdesc,
                                                   const int* __restrict__ col,
                                                   const float* __restrict__ dinv,
                                                   const float* __restrict__ bias,
                                                   float* __restrict__ out, int n) {
  const int tid = threadIdx.x;
  const int node = blockIdx.x * 32 + (tid >> 3);
  if (node >= n) return;
  const int cs = tid & 7;
  unsigned w = wdesc[node];
  int beg = (int)(w >> 10), nb = (int)(w & 1023);
  float a0, a1, a2, a3;
  {
    uint2 u = *(const uint2*)&gs[(size_t)node * 32 + cs * 4];
    a0 = bf_lo(u.x); a1 = bf_hi(u.x); a2 = bf_lo(u.y); a3 = bf_hi(u.y);
  }
  for (int i = 0; i < nb; i++) {
    int j = beg + i * 8;
    int4 sA = *(const int4*)&col[j];
    int4 sB = *(const int4*)&col[j + 4];
    uint2 u0 = *(const uint2*)&gs[(size_t)sA.x * 32 + cs * 4];
    uint2 u1 = *(const uint2*)&gs[(size_t)sA.y * 32 + cs * 4];
    uint2 u2 = *(const uint2*)&gs[(size_t)sA.z * 32 + cs * 4];
    uint2 u3 = *(const uint2*)&gs[(size_t)sA.w * 32 + cs * 4];
    uint2 u4 = *(const uint2*)&gs[(size_t)sB.x * 32 + cs * 4];
    uint2 u5 = *(const uint2*)&gs[(size_t)sB.y * 32 + cs * 4];
    uint2 u6 = *(const uint2*)&gs[(size_t)sB.z * 32 + cs * 4];
    uint2 u7 = *(const uint2*)&gs[(size_t)sB.w * 32 + cs * 4];
    a0 += bf_lo(u0.x); a1 += bf_hi(u0.x); a2 += bf_lo(u0.y); a3 += bf_hi(u0.y);
    a0 += bf_lo(u1.x); a1 += bf_hi(u1.x); a2 += bf_lo(u1.y); a3 += bf_hi(u1.y);
    a0 += bf_lo(u2.x); a1 += bf_hi(u2.x); a2 += bf_lo(u2.y); a3 += bf_hi(u2.y);
    a0 += bf_lo(u3.x); a1 += bf_hi(u3.x); a2 += bf_lo(u3.y); a3 += bf_hi(u3.y);
    a0 += bf_lo(u4.x); a1 += bf_hi(u4.x); a2 += bf_lo(u4.y); a3 += bf_hi(u4.y);
    a0 += bf_lo(u5.x); a1 += bf_hi(u5.x); a2 += bf_lo(u5.y); a3 += bf_hi(u5.y);
    a0 += bf_lo(u6.x); a1 += bf_hi(u6.x); a2 += bf_lo(u6.y); a3 += bf_hi(u6.y);
    a0 += bf_lo(u7.x); a1 += bf_hi(u7.x); a2 += bf_lo(u7.y); a3 += bf_hi(u7.y);
  }
  float di = dinv[node];
  float4 bv = *(const float4*)&bias[cs * 4];
  float4 o;
  o.x = a0 * di + bv.x; o.y = a1 * di + bv.y;
  o.z = a2 * di + bv.z; o.w = a3 * di + bv.w;
  o.x = o.x > 0.f ? o.x : 0.f;
  o.y = o.y > 0.f ? o.y : 0.f;
  o.z = o.z > 0.f ? o.z : 0.f;
  o.w = o.w > 0.f ? o.w : 0.f;
  *(float4*)&out[(size_t)node * 32 + cs * 4] = o;
}

// ---------------- launcher ----------------

extern "C" void kernel_launch(void* const* d_in, const int* in_sizes, int n_in,
                              void* d_out, int out_size, void* d_ws, size_t ws_size,
                              hipStream_t stream) {
  const float* x = (const float*)d_in[0];
  const int* ei = (const int*)d_in[1];
  const float* W1 = (const float*)d_in[2];
  const float* b1 = (const float*)d_in[3];
  const float* W2 = (const float*)d_in[4];
  const float* b2 = (const float*)d_in[5];

  const int N = in_sizes[0] / 128;
  const int E = in_sizes[1] / 2;
  const int* src = ei;
  const int* dst = ei + E;
  const int nb = (N + BSPAN - 1) >> BSHIFT;  // # coarse buckets (196 @ N=100K)

  char* p = (char*)d_ws;
  auto take = [&](size_t bytes) -> char* {
    char* q = p;
    p += (bytes + 255) & ~(size_t)255;
    return q;
  };
  int* bins = (int*)take((size_t)NB_MAX * CAP * 4);
  int* tail = (int*)take(NB_MAX * 4);
  unsigned* wdesc = (unsigned*)take((size_t)N * 4);
  int* col = (int*)take((size_t)nb * CAP2 * 4);
  float* dinv = (float*)take((size_t)N * 4);
  u16* g1 = (u16*)take((size_t)(N + 1) * 64 * 2);  // +1 zero row
  float* h = (float*)take((size_t)N * 64 * 4);
  u16* g2 = (u16*)take((size_t)(N + 1) * 32 * 2);  // +1 zero row

  hipMemsetAsync(tail, 0, NB_MAX * 4, stream);

  binpass<<<(E + EPBB - 1) / EPBB, BLK, 0, stream>>>(src, dst, E, bins, tail);
  bucket_sort<<<nb, BLK, 0, stream>>>(bins, tail, wdesc, col, dinv, N);

  gemm_mfma<128, 64, 2><<<(N + 127) / 128, BLK, 0, stream>>>(x, W1, dinv, g1, N);
  agg1_kernel<<<(N + 15) / 16, BLK, 0, stream>>>(g1, wdesc, col, dinv, b1, h, N);
  gemm_mfma<64, 32, 1><<<(N + 63) / 64, BLK, 0, stream>>>(h, W2, dinv, g2, N);
  agg2_kernel<<<(N + 31) / 32, BLK, 0, stream>>>(g2, wdesc, col, dinv, b2, (float*)d_out, N);
}

// Round 18
// 135.186 us; speedup vs baseline: 1.1694x; 1.0210x over previous
//
#include <hip/hip_runtime.h>
#include <math.h>

constexpr int BLK = 256;
constexpr int NB_MAX = 256;      // max coarse buckets (supports N <= 131072)
constexpr int BSHIFT = 9;        // 512 nodes per bucket
constexpr int BSPAN = 1 << BSHIFT;
constexpr int CAP = 10240;       // per-bucket bin capacity (mean 8192 @ E=1.6M, +22 sigma)
constexpr int CAP2 = 12800;      // per-bucket padded col capacity (mean 9984, +31 sigma)
constexpr int EPT2 = 16;         // edges per thread in binpass
constexpr int EPBB = BLK * EPT2; // 4096 edges per block

typedef unsigned short u16;
typedef __attribute__((ext_vector_type(8))) short short8_t;
typedef __attribute__((ext_vector_type(4))) float f32x4;

// ---- bf16 helpers ----
__device__ __forceinline__ u16 f2bf(float f) {
  union { float f; unsigned int i; } v;
  v.f = f;
  unsigned int r = v.i + 0x7FFF + ((v.i >> 16) & 1);  // RNE
  return (u16)(r >> 16);
}
__device__ __forceinline__ float bf_lo(unsigned u) {
  union { unsigned int i; float f; } v;
  v.i = u << 16;
  return v.f;
}
__device__ __forceinline__ float bf_hi(unsigned u) {
  union { unsigned int i; float f; } v;
  v.i = u & 0xFFFF0000u;
  return v.f;
}

// ---------------- pass 1: coarse binning, block-local sort for coalesced writes ----------------
// Edges are counting-sorted by bucket INSIDE the block (LDS stash), then written
// out in bucket order: consecutive threads write consecutive words of the same
// bucket run -> ~4-6x less write amplification than direct 4B scatter.
__global__ void __launch_bounds__(BLK) binpass(const int* __restrict__ src,
                                               const int* __restrict__ dst,
                                               int e, int* __restrict__ bins,
                                               int* __restrict__ tail) {
  __shared__ int lcnt[NB_MAX], lbase[NB_MAX], gbase[NB_MAX], lcur[NB_MAX], sd[BLK];
  __shared__ int stash[EPBB];   // 16KB packed values, bucket-ordered
  __shared__ u16 bkt[EPBB];     // 8KB bucket id per staged word
  const int tid = threadIdx.x;
  lcnt[tid] = 0;
  lcur[tid] = 0;
  __syncthreads();
  const int i0 = blockIdx.x * EPBB;
  int bb[EPT2], pk[EPT2];
#pragma unroll
  for (int k = 0; k < EPT2; k++) {
    int i = i0 + k * BLK + tid;
    if (i < e) {
      int d = dst[i], s = src[i];
      bb[k] = d >> BSHIFT;
      pk[k] = ((d & (BSPAN - 1)) << 23) | s;   // src < 2^23, dlo < 2^9
      atomicAdd(&lcnt[bb[k]], 1);
    } else {
      bb[k] = -1;
    }
  }
  __syncthreads();
  // block-exclusive scan of lcnt -> lbase; reserve global chunk per bucket
  int v = lcnt[tid];
  sd[tid] = v;
  __syncthreads();
  for (int off = 1; off < BLK; off <<= 1) {
    int t = (tid >= off) ? sd[tid - off] : 0;
    __syncthreads();
    sd[tid] += t;
    __syncthreads();
  }
  lbase[tid] = sd[tid] - v;
  gbase[tid] = atomicAdd(&tail[tid], v);
  __syncthreads();
  // stage into stash, bucket-ordered
#pragma unroll
  for (int k = 0; k < EPT2; k++) {
    if (bb[k] >= 0) {
      int idx = atomicAdd(&lcur[bb[k]], 1);
      int pos = lbase[bb[k]] + idx;
      stash[pos] = pk[k];
      bkt[pos] = (u16)bb[k];
    }
  }
  __syncthreads();
  // coalesced write-out: i-order == bucket order
  int total = e - i0;
  if (total > EPBB) total = EPBB;
  for (int i = tid; i < total; i += BLK) {
    int b = bkt[i];
    bins[b * CAP + gbase[b] + (i - lbase[b])] = stash[i];
  }
}

// ---------------- pass 2: per-bucket counting sort into FIXED col region ----------------
// Bucket b owns col[b*CAP2 .. b*CAP2+CAP2). Per-node segments padded to mult-of-8
// with pad entries = n (zero row). wdesc[node] = (beg<<10) | ceil(deg/8).
__global__ void __launch_bounds__(BLK) bucket_sort(const int* __restrict__ bins,
                                                   const int* __restrict__ tail,
                                                   unsigned* __restrict__ wdesc,
                                                   int* __restrict__ col,
                                                   float* __restrict__ dinv, int n) {
  __shared__ int hist[BSPAN], lpre[BSPAN], lcur[BSPAN], sd[BLK];
  const int b = blockIdx.x, tid = threadIdx.x;
  const int cnt = tail[b];
  const int base = b * CAP2;
  const int node0 = b << BSHIFT;
  const int nNodes = min(BSPAN, n - node0);
  const int* bin = bins + (size_t)b * CAP;

  hist[tid] = 0; hist[tid + BLK] = 0;
  lcur[tid] = 0; lcur[tid + BLK] = 0;
  __syncthreads();
  for (int j = tid; j < cnt; j += BLK) atomicAdd(&hist[(unsigned)bin[j] >> 23], 1);
  __syncthreads();
  // exclusive scan over PADDED counts (2 per thread)
  int h0 = hist[2 * tid], h1 = hist[2 * tid + 1];
  int p0 = (h0 + 7) & ~7, p1 = (h1 + 7) & ~7;
  int ts = p0 + p1;
  sd[tid] = ts;
  __syncthreads();
  for (int off = 1; off < BLK; off <<= 1) {
    int t = (tid >= off) ? sd[tid - off] : 0;
    __syncthreads();
    sd[tid] += t;
    __syncthreads();
  }
  int ex = sd[tid] - ts;
  lpre[2 * tid] = ex;
  lpre[2 * tid + 1] = ex + p0;
  __syncthreads();
  for (int d = tid; d < nNodes; d += BLK) {
    int hd = hist[d];
    int begd = base + lpre[d];
    wdesc[node0 + d] = ((unsigned)begd << 10) | (unsigned)((hd + 7) >> 3);
    dinv[node0 + d] = rsqrtf((float)hd + 1.0f);
    int pe = (hd + 7) & ~7;
    for (int t = hd; t < pe; t++) col[begd + t] = n;  // pad -> zero row
  }
  __syncthreads();
  for (int j = tid; j < cnt; j += BLK) {
    int pkv = bin[j];
    int dlo = (unsigned)pkv >> 23;
    int idx = atomicAdd(&lcur[dlo], 1);
    col[base + lpre[dlo] + idx] = pkv & 0x7FFFFF;
  }
}

// ---------------- MFMA GEMM via split-bf16: G = bf16((X @ W) * dinv) ----------------
// 3 MFMA per tile (hi*hi + lo*hi + hi*lo); fp32-grade accuracy. RT row-tiles of
// 64 rows per block amortize the one-time W staging. Block 0 zeroes pad row.
template <int K, int M, int RT>
__global__ void __launch_bounds__(BLK) gemm_mfma(const float* __restrict__ X,
                                                 const float* __restrict__ W,
                                                 const float* __restrict__ dinv,
                                                 u16* __restrict__ G, int n) {
  constexpr int KC = K / 32;   // K-chunks
  constexpr int CT = M / 16;   // 16-col tiles
  constexpr int PADK = K + 8;  // row stride 272B (K=128): 2-way bank alias = free
  __shared__ u16 wt_hi[M][PADK];
  __shared__ u16 wt_lo[M][PADK];
  const int tid = threadIdx.x;
  const int lane = tid & 63;
  const int wv = tid >> 6;

  if (blockIdx.x == 0 && tid < M) G[(size_t)n * M + tid] = 0;  // zero pad row

  // stage W transposed + hi/lo split (one-time; reads coalesced)
  for (int i = tid; i < K * M; i += BLK) {
    int k = i / M, m = i % M;
    float w = W[i];
    unsigned wb = __float_as_uint(w);
    wt_hi[m][k] = (u16)(wb >> 16);                       // truncation hi
    wt_lo[m][k] = f2bf(w - __uint_as_float(wb & 0xFFFF0000u));
  }
  __syncthreads();

  const int r16 = lane & 15;
  const int oct = lane >> 4;

#pragma unroll
  for (int rt = 0; rt < RT; rt++) {
    int rowA = blockIdx.x * (64 * RT) + rt * 64 + wv * 16 + r16;
    if (rowA >= n) rowA = n - 1;  // clamp (stores guarded)

    f32x4 acc[CT];
#pragma unroll
    for (int ct = 0; ct < CT; ct++) acc[ct] = (f32x4){0.f, 0.f, 0.f, 0.f};

#pragma unroll
    for (int kc = 0; kc < KC; kc++) {
      const float* xp = &X[(size_t)rowA * K + kc * 32 + oct * 8];
      float4 v0 = *(const float4*)xp;
      float4 v1 = *(const float4*)(xp + 4);
      float vv[8] = {v0.x, v0.y, v0.z, v0.w, v1.x, v1.y, v1.z, v1.w};
      short8_t ahi, alo;
#pragma unroll
      for (int j = 0; j < 8; j++) {
        unsigned xb = __float_as_uint(vv[j]);
        ahi[j] = (short)(xb >> 16);  // truncation hi
        alo[j] = (short)f2bf(vv[j] - __uint_as_float(xb & 0xFFFF0000u));
      }
#pragma unroll
      for (int ct = 0; ct < CT; ct++) {
        short8_t bhi = *(const short8_t*)&wt_hi[ct * 16 + r16][kc * 32 + oct * 8];
        short8_t blo = *(const short8_t*)&wt_lo[ct * 16 + r16][kc * 32 + oct * 8];
        acc[ct] = __builtin_amdgcn_mfma_f32_16x16x32_bf16(ahi, bhi, acc[ct], 0, 0, 0);
        acc[ct] = __builtin_amdgcn_mfma_f32_16x16x32_bf16(alo, bhi, acc[ct], 0, 0, 0);
        acc[ct] = __builtin_amdgcn_mfma_f32_16x16x32_bf16(ahi, blo, acc[ct], 0, 0, 0);
      }
    }

    // epilogue: C row = oct*4 + reg, col = ct*16 + r16
    const int rbase = blockIdx.x * (64 * RT) + rt * 64 + wv * 16 + oct * 4;
    float dv[4];
#pragma unroll
    for (int r = 0; r < 4; r++) {
      int gr = rbase + r;
      dv[r] = (gr < n) ? dinv[gr] : 0.f;
    }
#pragma unroll
    for (int ct = 0; ct < CT; ct++) {
#pragma unroll
      for (int r = 0; r < 4; r++) {
        int gr = rbase + r;
        if (gr < n) G[(size_t)gr * M + ct * 16 + r16] = f2bf(acc[ct][r] * dv[r]);
      }
    }
  }
}

// ---------------- aggregation (one node per lane-group, no shuffles) ----------------
// gs (bf16, N+1 rows; row n zero). Segments padded to mult-of-8 with col=n.

// layer 1: 16 lanes per node (cs = 4-channel slice). Per iter: 2 broadcast int4
// col loads + 8 row gathers (128B line each) + 32 unpack-adds per lane.
__global__ void __launch_bounds__(BLK) agg1_kernel(const u16* __restrict__ gs,
                                                   const unsigned* __restrict__ wdesc,
                                                   const int* __restrict__ col,
                                                   const float* __restrict__ dinv,
                                                   const float* __restrict__ bias,
                                                   float* __restrict__ out, int n) {
  const int tid = threadIdx.x;
  const int node = blockIdx.x * 16 + (tid >> 4);
  if (node >= n) return;
  const int cs = tid & 15;
  unsigned w = wdesc[node];
  int beg = (int)(w >> 10), nb = (int)(w & 1023);
  float a0, a1, a2, a3;
  {  // self-loop slice (unconditional: this group owns the node)
    uint2 u = *(const uint2*)&gs[(size_t)node * 64 + cs * 4];
    a0 = bf_lo(u.x); a1 = bf_hi(u.x); a2 = bf_lo(u.y); a3 = bf_hi(u.y);
  }
  for (int i = 0; i < nb; i++) {
    int j = beg + i * 8;
    int4 sA = *(const int4*)&col[j];
    int4 sB = *(const int4*)&col[j + 4];
    uint2 u0 = *(const uint2*)&gs[(size_t)sA.x * 64 + cs * 4];
    uint2 u1 = *(const uint2*)&gs[(size_t)sA.y * 64 + cs * 4];
    uint2 u2 = *(const uint2*)&gs[(size_t)sA.z * 64 + cs * 4];
    uint2 u3 = *(const uint2*)&gs[(size_t)sA.w * 64 + cs * 4];
    uint2 u4 = *(const uint2*)&gs[(size_t)sB.x * 64 + cs * 4];
    uint2 u5 = *(const uint2*)&gs[(size_t)sB.y * 64 + cs * 4];
    uint2 u6 = *(const uint2*)&gs[(size_t)sB.z * 64 + cs * 4];
    uint2 u7 = *(const uint2*)&gs[(size_t)sB.w * 64 + cs * 4];
    a0 += bf_lo(u0.x); a1 += bf_hi(u0.x); a2 += bf_lo(u0.y); a3 += bf_hi(u0.y);
    a0 += bf_lo(u1.x); a1 += bf_hi(u1.x); a2 += bf_lo(u1.y); a3 += bf_hi(u1.y);
    a0 += bf_lo(u2.x); a1 += bf_hi(u2.x); a2 += bf_lo(u2.y); a3 += bf_hi(u2.y);
    a0 += bf_lo(u3.x); a1 += bf_hi(u3.x); a2 += bf_lo(u3.y); a3 += bf_hi(u3.y);
    a0 += bf_lo(u4.x); a1 += bf_hi(u4.x); a2 += bf_lo(u4.y); a3 += bf_hi(u4.y);
    a0 += bf_lo(u5.x); a1 += bf_hi(u5.x); a2 += bf_lo(u5.y); a3 += bf_hi(u5.y);
    a0 += bf_lo(u6.x); a1 += bf_hi(u6.x); a2 += bf_lo(u6.y); a3 += bf_hi(u6.y);
    a0 += bf_lo(u7.x); a1 += bf_hi(u7.x); a2 += bf_lo(u7.y); a3 += bf_hi(u7.y);
  }
  float di = dinv[node];
  float4 bv = *(const float4*)&bias[cs * 4];
  float4 o;
  o.x = a0 * di + bv.x; o.y = a1 * di + bv.y;
  o.z = a2 * di + bv.z; o.w = a3 * di + bv.w;
  o.x = o.x > 0.f ? o.x : 0.f;
  o.y = o.y > 0.f ? o.y : 0.f;
  o.z = o.z > 0.f ? o.z : 0.f;
  o.w = o.w > 0.f ? o.w : 0.f;
  *(float4*)&out[(size_t)node * 64 + cs * 4] = o;
}

// layer 2: 8 lanes per node (cs = 4-channel slice of 32). Same batch structure.
__global__ void __launch_bounds__(BLK) agg2_kernel(const u16* __restrict__ gs,
                                                   const unsigned* __restrict__ wdesc,
                                                   const int* __restrict__ col,
                                                   const float* __restrict__ dinv,
                                                   const float* __restrict__ bias,
                                                   float* __restrict__ out, int n) {
  const int tid = threadIdx.x;
  const int node = blockIdx.x * 32 + (tid >> 3);
  if (node >= n) return;
  const int cs = tid & 7;
  unsigned w = wdesc[node];
  int beg = (int)(w >> 10), nb = (int)(w & 1023);
  float a0, a1, a2, a3;
  {
    uint2 u = *(const uint2*)&gs[(size_t)node * 32 + cs * 4];
    a0 = bf_lo(u.x); a1 = bf_hi(u.x); a2 = bf_lo(u.y); a3 = bf_hi(u.y);
  }
  for (int i = 0; i < nb; i++) {
    int j = beg + i * 8;
    int4 sA = *(const int4*)&col[j];
    int4 sB = *(const int4*)&col[j + 4];
    uint2 u0 = *(const uint2*)&gs[(size_t)sA.x * 32 + cs * 4];
    uint2 u1 = *(const uint2*)&gs[(size_t)sA.y * 32 + cs * 4];
    uint2 u2 = *(const uint2*)&gs[(size_t)sA.z * 32 + cs * 4];
    uint2 u3 = *(const uint2*)&gs[(size_t)sA.w * 32 + cs * 4];
    uint2 u4 = *(const uint2*)&gs[(size_t)sB.x * 32 + cs * 4];
    uint2 u5 = *(const uint2*)&gs[(size_t)sB.y * 32 + cs * 4];
    uint2 u6 = *(const uint2*)&gs[(size_t)sB.z * 32 + cs * 4];
    uint2 u7 = *(const uint2*)&gs[(size_t)sB.w * 32 + cs * 4];
    a0 += bf_lo(u0.x); a1 += bf_hi(u0.x); a2 += bf_lo(u0.y); a3 += bf_hi(u0.y);
    a0 += bf_lo(u1.x); a1 += bf_hi(u1.x); a2 += bf_lo(u1.y); a3 += bf_hi(u1.y);
    a0 += bf_lo(u2.x); a1 += bf_hi(u2.x); a2 += bf_lo(u2.y); a3 += bf_hi(u2.y);
    a0 += bf_lo(u3.x); a1 += bf_hi(u3.x); a2 += bf_lo(u3.y); a3 += bf_hi(u3.y);
    a0 += bf_lo(u4.x); a1 += bf_hi(u4.x); a2 += bf_lo(u4.y); a3 += bf_hi(u4.y);
    a0 += bf_lo(u5.x); a1 += bf_hi(u5.x); a2 += bf_lo(u5.y); a3 += bf_hi(u5.y);
    a0 += bf_lo(u6.x); a1 += bf_hi(u6.x); a2 += bf_lo(u6.y); a3 += bf_hi(u6.y);
    a0 += bf_lo(u7.x); a1 += bf_hi(u7.x); a2 += bf_lo(u7.y); a3 += bf_hi(u7.y);
  }
  float di = dinv[node];
  float4 bv = *(const float4*)&bias[cs * 4];
  float4 o;
  o.x = a0 * di + bv.x; o.y = a1 * di + bv.y;
  o.z = a2 * di + bv.z; o.w = a3 * di + bv.w;
  o.x = o.x > 0.f ? o.x : 0.f;
  o.y = o.y > 0.f ? o.y : 0.f;
  o.z = o.z > 0.f ? o.z : 0.f;
  o.w = o.w > 0.f ? o.w : 0.f;
  *(float4*)&out[(size_t)node * 32 + cs * 4] = o;
}

// ---------------- launcher ----------------

extern "C" void kernel_launch(void* const* d_in, const int* in_sizes, int n_in,
                              void* d_out, int out_size, void* d_ws, size_t ws_size,
                              hipStream_t stream) {
  const float* x = (const float*)d_in[0];
  const int* ei = (const int*)d_in[1];
  const float* W1 = (const float*)d_in[2];
  const float* b1 = (const float*)d_in[3];
  const float* W2 = (const float*)d_in[4];
  const float* b2 = (const float*)d_in[5];

  const int N = in_sizes[0] / 128;
  const int E = in_sizes[1] / 2;
  const int* src = ei;
  const int* dst = ei + E;
  const int nb = (N + BSPAN - 1) >> BSHIFT;  // # coarse buckets (196 @ N=100K)

  char* p = (char*)d_ws;
  auto take = [&](size_t bytes) -> char* {
    char* q = p;
    p += (bytes + 255) & ~(size_t)255;
    return q;
  };
  int* bins = (int*)take((size_t)NB_MAX * CAP * 4);
  int* tail = (int*)take(NB_MAX * 4);
  unsigned* wdesc = (unsigned*)take((size_t)N * 4);
  int* col = (int*)take((size_t)nb * CAP2 * 4);
  float* dinv = (float*)take((size_t)N * 4);
  u16* g1 = (u16*)take((size_t)(N + 1) * 64 * 2);  // +1 zero row
  float* h = (float*)take((size_t)N * 64 * 4);
  u16* g2 = (u16*)take((size_t)(N + 1) * 32 * 2);  // +1 zero row

  hipMemsetAsync(tail, 0, NB_MAX * 4, stream);

  binpass<<<(E + EPBB - 1) / EPBB, BLK, 0, stream>>>(src, dst, E, bins, tail);
  bucket_sort<<<nb, BLK, 0, stream>>>(bins, tail, wdesc, col, dinv, N);

  gemm_mfma<128, 64, 2><<<(N + 127) / 128, BLK, 0, stream>>>(x, W1, dinv, g1, N);
  agg1_kernel<<<(N + 15) / 16, BLK, 0, stream>>>(g1, wdesc, col, dinv, b1, h, N);
  gemm_mfma<64, 32, 1><<<(N + 63) / 64, BLK, 0, stream>>>(h, W2, dinv, g2, N);
  agg2_kernel<<<(N + 31) / 32, BLK, 0, stream>>>(g2, wdesc, col, dinv, b2, (float*)d_out, N);
}